// Round 2
// 7229.716 us; speedup vs baseline: 1.3978x; 1.3978x over previous
//
#include <hip/hip_runtime.h>
#include <cstddef>
#include <cstdint>

#define BB 16
#define TT 1024
#define HH 512
#define R1S 4   // h1 ring slots
#define R2S 2   // h2 ring slots

typedef __attribute__((address_space(1))) const unsigned int GBUF;
typedef __attribute__((address_space(3))) unsigned int LBUF;

// async global->LDS, 16 B/lane; LDS dst = wave-uniform base + lane*16 (x / h0 only)
__device__ __forceinline__ void gl_lds16(const float* g, float* l) {
    __builtin_amdgcn_global_load_lds((GBUF*)g, (LBUF*)l, 16, 0, 0);
}

// ballot-poll one 128-flag bank: wait until flags[base..base+127] all >= need
__device__ __forceinline__ void poll_bank(const int* flags, int base, int need) {
    const int lane = threadIdx.x & 63;
    for (;;) {
        int a = __hip_atomic_load(&flags[base + lane],      __ATOMIC_RELAXED, __HIP_MEMORY_SCOPE_AGENT);
        int b = __hip_atomic_load(&flags[base + lane + 64], __ATOMIC_RELAXED, __HIP_MEMORY_SCOPE_AGENT);
        if (__ballot((a >= need) && (b >= need)) == ~0ull) break;
        __builtin_amdgcn_s_sleep(1);
    }
}

// Stage one 256-float k-half of all 16 rows (16 KB) from an agent-coherent ring:
// sc1 loads (bypass non-coherent per-XCD L2, read at LLC) -> VGPRs -> ds_write_b128.
// Own-wave stages, own-wave reads: in-wave vmcnt/program-order LDS suffice. No fences.
__device__ __forceinline__ void stage_half_sc1(const float* src, float* dstlds,
                                               int p, int lane) {
    const float* g = src    + p * 256 + lane * 4;
    float*       l = dstlds + p * 256 + lane * 4;
    float4 v[16];
    #pragma unroll
    for (int b = 0; b < 16; ++b) {
        const float* gp = g + (size_t)b * HH;
        asm volatile("global_load_dwordx4 %0, %1, off sc1"
                     : "=v"(v[b]) : "v"(gp));
    }
    asm volatile("s_waitcnt vmcnt(0)" ::: "memory");
    #pragma unroll
    for (int b = 0; b < 16; ++b)
        *(float4*)(l + (size_t)b * HH) = v[b];
}

// 256 WGs x 256 threads, 1 WG/CU. layer = wg>>7, lw = wg&127 owns h cols lw*4..+3.
// R7 = R5 sync skeleton (proven) + rows_per_lane=2 compute (halves ds_read_b128)
//      + slot-rotated conflict-free partial writes (pitch 33, 32 slots).
// The R6 half-bank-poll / raw-barrier edits are reverted pending race bisection.
__global__ __launch_bounds__(256, 1)
void lstm2_flow8(const float* __restrict__ x,
                 const float* __restrict__ h0,
                 const float* __restrict__ c0,
                 const float* __restrict__ w_ih0, const float* __restrict__ w_hh0,
                 const float* __restrict__ b_ih0, const float* __restrict__ b_hh0,
                 const float* __restrict__ w_ih1, const float* __restrict__ w_hh1,
                 const float* __restrict__ b_ih1, const float* __restrict__ b_hh1,
                 float* __restrict__ out,
                 int*   __restrict__ flags,    // [256] zeroed pre-launch; [0..127]=L0, [128..255]=L1
                 float* __restrict__ h1ring,   // [R1S][BB][HH]
                 float* __restrict__ h2ring)   // [R2S][BB][HH]
{
    __shared__ float act0[2 * BB * HH];   // L0: x(t) double-buffered; L1: h1(t) in slot 0
    __shared__ float act1[BB * HH];       // own h(t-1)
    __shared__ float partial[16 * 16 * 33];   // [row16][b16][32 slots + pad]
    __shared__ float gval[16 * 16];
    __shared__ float bias_lds[16];

    const int tid   = threadIdx.x;
    const int wg    = blockIdx.x;
    const int layer = wg >> 7;
    const int lw    = wg & 127;

    const float* w_in  = layer ? w_ih1 : w_ih0;
    const float* w_rec = layer ? w_hh1 : w_hh0;
    const float* b_in  = layer ? b_ih1 : b_ih0;
    const float* b_rec = layer ? b_hh1 : b_hh0;
    float* ring_own    = layer ? h2ring : h1ring;
    const int rmask    = layer ? (R2S - 1) : (R1S - 1);

    const int lane = tid & 63;
    const int wv   = tid >> 6;     // 0..3
    const int mat  = wv & 1;       // 0: input matrix, 1: recurrent matrix
    const int p    = wv >> 1;      // k half
    const int kc   = lane & 7;     // k-chunk: floats kc*4 + q*32, q=0..7
    const int r2   = lane >> 3;    // row-pair 0..7 -> rows 2*r2, 2*r2+1

    // ---- one-time: weights -> 64 VGPRs/thread (2 rows x 8 float4) ----
    float4 wreg[2][8];
    {
        #pragma unroll
        for (int i = 0; i < 2; ++i) {
            const int r = r2 * 2 + i;
            const int gate = r >> 2, jj = r & 3;
            const int grow = gate * HH + lw * 4 + jj;
            const float* wsrc = (mat ? w_rec : w_in) + (size_t)grow * HH + p * 256 + kc * 4;
            #pragma unroll
            for (int q = 0; q < 8; ++q)
                wreg[i][q] = *(const float4*)(wsrc + q * 32);
        }
    }
    if (tid < 16) {
        const int g2 = tid >> 2, j2 = tid & 3;
        const int gr = g2 * HH + lw * 4 + j2;
        bias_lds[tid] = b_in[gr] + b_rec[gr];
    }
    float c_reg = 0.f;
    if (tid < 64) {
        const int jj = tid & 3, b = tid >> 2;
        c_reg = c0[(size_t)layer * BB * HH + (size_t)b * HH + lw * 4 + jj];
    }
    // pre-stage x(0) (L0, input waves): each wave stages its own k-columns of all b rows
    if (layer == 0 && mat == 0) {
        #pragma unroll
        for (int b = 0; b < 16; ++b)
            gl_lds16(x + ((size_t)b * TT) * HH + p * 256 + lane * 4,
                     act0 + b * HH + p * 256);
    }
    __syncthreads();

    // slot rotation: bijective per row (sum over slots is order-free); spreads the
    // per-instruction partial-write banks 2-way (free) instead of 8-way.
    const int slot = ((mat << 4) + (p << 3) + kc + (r2 << 2)) & 31;

    auto compute_half = [&](const float* abase) {
        const float* ab0 = abase + p * 256 + kc * 4;
        float* pw0 = partial + (size_t)((r2 * 2 + 0) * 16) * 33 + slot;
        float* pw1 = partial + (size_t)((r2 * 2 + 1) * 16) * 33 + slot;
        for (int b = 0; b < 16; ++b) {
            const float* ab = ab0 + (size_t)b * HH;
            float x0 = 0.f, y0 = 0.f, z0 = 0.f, w0 = 0.f;
            float x1 = 0.f, y1 = 0.f, z1 = 0.f, w1 = 0.f;
            #pragma unroll
            for (int q = 0; q < 8; ++q) {
                float4 av = *(const float4*)(ab + q * 32);
                x0 += wreg[0][q].x * av.x;
                y0 += wreg[0][q].y * av.y;
                z0 += wreg[0][q].z * av.z;
                w0 += wreg[0][q].w * av.w;
                x1 += wreg[1][q].x * av.x;
                y1 += wreg[1][q].y * av.y;
                z1 += wreg[1][q].z * av.z;
                w1 += wreg[1][q].w * av.w;
            }
            pw0[b * 33] = (x0 + y0) + (z0 + w0);
            pw1[b * 33] = (x1 + y1) + (z1 + w1);
        }
    };

    for (int t = 0; t < TT; ++t) {
        // ======== phase A: per-wave specialized (no cross-wave deps) ========
        if (mat == 0) {
            if (layer == 1) {
                poll_bank(flags, 0, t + 1);                    // h1(t) published by all L0
                const float* s0 = h1ring + (size_t)(t & (R1S - 1)) * BB * HH;
                stage_half_sc1(s0, act0, p, lane);
            }
            asm volatile("s_waitcnt vmcnt(0)" ::: "memory");   // x prefetch (L0) staged
            compute_half(act0 + ((layer == 0) ? (t & 1) * BB * HH : 0));
        } else {
            if (t == 0) {
                const float* s1 = h0 + (size_t)layer * BB * HH;
                #pragma unroll
                for (int b = 0; b < 16; ++b)
                    gl_lds16(s1 + (size_t)b * HH + p * 256 + lane * 4,
                             act1 + b * HH + p * 256);
                asm volatile("s_waitcnt vmcnt(0)" ::: "memory");
            } else {
                if (layer == 0) {
                    poll_bank(flags, 0, t);                    // h1(t-1) published
                    if (t >= R1S) poll_bank(flags, 128, t - (R1S - 1));  // ring safety
                } else {
                    poll_bank(flags, 128, t);                  // h2(t-1) published
                }
                const float* s1 = ring_own + (size_t)((t - 1) & rmask) * BB * HH;
                stage_half_sc1(s1, act1, p, lane);
            }
            compute_half(act1);
        }
        __syncthreads();

        // ======== phase B: reduce + gates + publish ========
        {
            const int rr = tid >> 4, b = tid & 15;
            const float* pp = partial + (size_t)(rr * 16 + b) * 33;
            float s0 = bias_lds[rr], s1 = 0.f, s2 = 0.f, s3 = 0.f;
            #pragma unroll
            for (int q = 0; q < 32; q += 4) {
                s0 += pp[q + 0];
                s1 += pp[q + 1];
                s2 += pp[q + 2];
                s3 += pp[q + 3];
            }
            gval[rr * 16 + b] = (s0 + s1) + (s2 + s3);
        }
        __syncthreads();

        if (tid < 64) {
            const int jj = tid & 3, b = tid >> 2;
            const float gi = gval[(0  + jj) * 16 + b];
            const float gf = gval[(4  + jj) * 16 + b];
            const float gg = gval[(8  + jj) * 16 + b];
            const float go = gval[(12 + jj) * 16 + b];
            const float i_ = 1.f / (1.f + __expf(-gi));
            const float f_ = 1.f / (1.f + __expf(-gf));
            const float g_ = tanhf(gg);
            const float o_ = 1.f / (1.f + __expf(-go));
            c_reg = f_ * c_reg + i_ * g_;
            const float h_ = o_ * tanhf(c_reg);
            // publish: agent-scope relaxed store -> sc1 write-through at LLC
            float* dst = ring_own + (size_t)(t & rmask) * BB * HH + (size_t)b * HH + lw * 4 + jj;
            __hip_atomic_store(dst, h_, __ATOMIC_RELAXED, __HIP_MEMORY_SCOPE_AGENT);
            if (t == TT - 1)
                out[(size_t)layer * BB * HH + (size_t)b * HH + lw * 4 + jj] = h_;
        }
        // hand-built release: wave0's h stores complete at LLC, then flag store
        asm volatile("s_waitcnt vmcnt(0)" ::: "memory");
        if (tid == 0)
            __hip_atomic_store(&flags[wg], t + 1, __ATOMIC_RELAXED, __HIP_MEMORY_SCOPE_AGENT);
        // x(t+1) prefetch AFTER the publish (off the release path); same wave
        // writes/reads its own act0 slot -> program-order safe.
        if (layer == 0 && mat == 0 && t + 1 < TT) {
            float* l0 = act0 + ((t + 1) & 1) * BB * HH;
            #pragma unroll
            for (int b = 0; b < 16; ++b)
                gl_lds16(x + ((size_t)b * TT + (t + 1)) * HH + p * 256 + lane * 4,
                         l0 + b * HH + p * 256);
        }
        __syncthreads();
    }
}

extern "C" void kernel_launch(void* const* d_in, const int* in_sizes, int n_in,
                              void* d_out, int out_size, void* d_ws, size_t ws_size,
                              hipStream_t stream) {
    const float* xp   = (const float*)d_in[0];
    const float* h0p  = (const float*)d_in[1];
    const float* c0p  = (const float*)d_in[2];
    const float* wih0 = (const float*)d_in[3];
    const float* whh0 = (const float*)d_in[4];
    const float* bih0 = (const float*)d_in[5];
    const float* bhh0 = (const float*)d_in[6];
    const float* wih1 = (const float*)d_in[7];
    const float* whh1 = (const float*)d_in[8];
    const float* bih1 = (const float*)d_in[9];
    const float* bhh1 = (const float*)d_in[10];
    float* outp = (float*)d_out;

    int*   flags  = (int*)d_ws;                        // [256]
    float* h1ring = (float*)d_ws + 1024;               // 4 KB offset; 128 KB
    float* h2ring = h1ring + R1S * BB * HH;            // 64 KB

    hipMemsetAsync(d_ws, 0, 4096, stream);             // zero flags

    void* args[] = { &xp, &h0p, &c0p, &wih0, &whh0, &bih0, &bhh0,
                     &wih1, &whh1, &bih1, &bhh1, &outp, &flags, &h1ring, &h2ring };
    hipLaunchCooperativeKernel(lstm2_flow8, dim3(256), dim3(256), args, 0, stream);
}